// Round 1
// baseline (1611.301 us; speedup 1.0000x reference)
//
#include <hip/hip_runtime.h>
#include <hip/hip_bf16.h>

// ---------------------------------------------------------------------------
// AttentionModule: per-head QKV proj + LN -> QK^T/11 -> softmax over BATCH
// axis (quirk: Z[h,n,m] = sum_b exp(s)) -> PV -> concat heads -> MLP(relu x2)
// -> residual -> affine LN.
// Round 1: fp32 VALU baseline, bf16 staging in ws (~140 MB):
//   Qw/Kw/Vw [B,H,N,128] bf16, Acat [B,N,512] bf16, h1 [B,N,128] bf16,
//   Z [H,N,N] fp32.
// ---------------------------------------------------------------------------

constexpr int Bc = 64, Nc = 512, Ec = 128, Hc = 4;
constexpr float SCALEc = 1.0f / 11.0f;   // int(sqrt(128)) == 11 (faithful)
constexpr float EPSc = 1e-5f;
constexpr size_t QKV_SZ = (size_t)Bc * Hc * Nc * Ec;  // 16,777,216 elems

static __device__ __forceinline__ float bf2f(unsigned short u) {
  return __uint_as_float(((unsigned int)u) << 16);
}
static __device__ __forceinline__ unsigned short f2bf(float f) {
  unsigned int x = __float_as_uint(f);
  x += 0x7fffu + ((x >> 16) & 1u);  // RNE
  return (unsigned short)(x >> 16);
}
static __device__ __forceinline__ void bf8_to_f(const uint4 u, float* o) {
  o[0] = __uint_as_float(u.x << 16); o[1] = __uint_as_float(u.x & 0xffff0000u);
  o[2] = __uint_as_float(u.y << 16); o[3] = __uint_as_float(u.y & 0xffff0000u);
  o[4] = __uint_as_float(u.z << 16); o[5] = __uint_as_float(u.z & 0xffff0000u);
  o[6] = __uint_as_float(u.w << 16); o[7] = __uint_as_float(u.w & 0xffff0000u);
}
static __device__ __forceinline__ float red16(float v) {
  v += __shfl_xor(v, 1);
  v += __shfl_xor(v, 2);
  v += __shfl_xor(v, 4);
  v += __shfl_xor(v, 8);
  return v;
}

// ---------------------------------------------------------------------------
// Kernel 1: Q/K/V projection + bias + LayerNorm(no affine), output bf16.
// grid (512 row-tiles, 12 = proj*4+h), block 256.
// Each block: 64 rows of x [32768,128] x W[h] [128,128] -> 64x128 + LN.
// ---------------------------------------------------------------------------
__global__ __launch_bounds__(256) void k_qkv(
    const float* __restrict__ x,
    const float* __restrict__ Wq, const float* __restrict__ bq,
    const float* __restrict__ Wk, const float* __restrict__ bk,
    const float* __restrict__ Wv, const float* __restrict__ bv,
    unsigned short* __restrict__ ws0) {
  __shared__ float xs[64][132];
  __shared__ float wt[64][132];
  const int tid = threadIdx.x;
  const int proj = blockIdx.y >> 2;
  const int h = blockIdx.y & 3;
  const float* W = (proj == 0 ? Wq : (proj == 1 ? Wk : Wv)) + (size_t)h * Ec * Ec;
  const float* bias = (proj == 0 ? bq : (proj == 1 ? bk : bv)) + h * Ec;
  const int r0 = blockIdx.x * 64;
  const int b = r0 >> 9;
  const int n0 = r0 & 511;
  unsigned short* outp = ws0 + (size_t)proj * QKV_SZ + ((size_t)(b * Hc + h) * Nc + n0) * Ec;

#pragma unroll
  for (int i = 0; i < 8; ++i) {  // x tile 64x128 fp32
    int f = tid + i * 256;
    int row = f >> 5, c4 = (f & 31) * 4;
    *(float4*)&xs[row][c4] = *(const float4*)(x + (size_t)(r0 + row) * Ec + c4);
  }

  float acc[4][8];
#pragma unroll
  for (int i = 0; i < 4; ++i)
#pragma unroll
    for (int j = 0; j < 8; ++j) acc[i][j] = 0.f;

  const int g = tid >> 4, c = tid & 15;

  for (int kt = 0; kt < Ec; kt += 64) {
#pragma unroll
    for (int i = 0; i < 8; ++i) {  // W rows kt..kt+63 x 128
      int f = tid + i * 256;
      int row = f >> 5, c4 = (f & 31) * 4;
      *(float4*)&wt[row][c4] = *(const float4*)(W + (size_t)(kt + row) * Ec + c4);
    }
    __syncthreads();
#pragma unroll 4
    for (int k = 0; k < 64; ++k) {
      const float a0 = xs[g * 4 + 0][kt + k], a1 = xs[g * 4 + 1][kt + k];
      const float a2 = xs[g * 4 + 2][kt + k], a3 = xs[g * 4 + 3][kt + k];
      float bb[8];
#pragma unroll
      for (int j = 0; j < 8; ++j) bb[j] = wt[k][c + 16 * j];
#pragma unroll
      for (int j = 0; j < 8; ++j) {
        acc[0][j] = fmaf(a0, bb[j], acc[0][j]);
        acc[1][j] = fmaf(a1, bb[j], acc[1][j]);
        acc[2][j] = fmaf(a2, bb[j], acc[2][j]);
        acc[3][j] = fmaf(a3, bb[j], acc[3][j]);
      }
    }
    __syncthreads();
  }

  float bv8[8];
#pragma unroll
  for (int j = 0; j < 8; ++j) bv8[j] = bias[c + 16 * j];
#pragma unroll
  for (int i = 0; i < 4; ++i) {
    float s = 0.f, s2 = 0.f;
#pragma unroll
    for (int j = 0; j < 8; ++j) {
      float v = acc[i][j] + bv8[j];
      acc[i][j] = v; s += v; s2 += v * v;
    }
    s = red16(s); s2 = red16(s2);
    const float mu = s * (1.f / 128.f);
    const float inv = rsqrtf(s2 * (1.f / 128.f) - mu * mu + EPSc);
    const int row = g * 4 + i;
#pragma unroll
    for (int j = 0; j < 8; ++j)
      outp[(size_t)row * Ec + c + 16 * j] = f2bf((acc[i][j] - mu) * inv);
  }
}

// ---------------------------------------------------------------------------
// Kernel 2: Z[h,n,m] = sum_b exp(Q[b,h,n,:].K[b,h,m,:] / 11).
// grid (nt=8, mt=8, h=4), block 256; loop b=0..63 inside.
// ---------------------------------------------------------------------------
__global__ __launch_bounds__(256) void k_z(
    const unsigned short* __restrict__ Qw, const unsigned short* __restrict__ Kw,
    float* __restrict__ Z) {
  __shared__ float qs[64][132];
  __shared__ float ks[64][132];
  const int tid = threadIdx.x;
  const int nt = blockIdx.x, mt = blockIdx.y, h = blockIdx.z;
  const int g = tid >> 4, c = tid & 15;
  float zacc[4][4];
#pragma unroll
  for (int i = 0; i < 4; ++i)
#pragma unroll
    for (int j = 0; j < 4; ++j) zacc[i][j] = 0.f;

  for (int b = 0; b < Bc; ++b) {
    const unsigned short* qsrc = Qw + ((size_t)(b * Hc + h) * Nc + nt * 64) * Ec;
    const unsigned short* ksrc = Kw + ((size_t)(b * Hc + h) * Nc + mt * 64) * Ec;
#pragma unroll
    for (int i = 0; i < 4; ++i) {  // 1024 ushort8 units per tile, 4/thread
      int f = tid + i * 256;
      int row = f >> 4, c8 = (f & 15) * 8;
      float o[8];
      bf8_to_f(*(const uint4*)(qsrc + (size_t)row * Ec + c8), o);
      *(float4*)&qs[row][c8] = make_float4(o[0], o[1], o[2], o[3]);
      *(float4*)&qs[row][c8 + 4] = make_float4(o[4], o[5], o[6], o[7]);
      bf8_to_f(*(const uint4*)(ksrc + (size_t)row * Ec + c8), o);
      *(float4*)&ks[row][c8] = make_float4(o[0], o[1], o[2], o[3]);
      *(float4*)&ks[row][c8 + 4] = make_float4(o[4], o[5], o[6], o[7]);
    }
    __syncthreads();
    float s[4][4];
#pragma unroll
    for (int i = 0; i < 4; ++i)
#pragma unroll
      for (int j = 0; j < 4; ++j) s[i][j] = 0.f;
#pragma unroll 2
    for (int k = 0; k < 128; ++k) {
      const float a0 = qs[g * 4 + 0][k], a1 = qs[g * 4 + 1][k];
      const float a2 = qs[g * 4 + 2][k], a3 = qs[g * 4 + 3][k];
#pragma unroll
      for (int j = 0; j < 4; ++j) {
        const float bb = ks[c + 16 * j][k];
        s[0][j] = fmaf(a0, bb, s[0][j]);
        s[1][j] = fmaf(a1, bb, s[1][j]);
        s[2][j] = fmaf(a2, bb, s[2][j]);
        s[3][j] = fmaf(a3, bb, s[3][j]);
      }
    }
    __syncthreads();
#pragma unroll
    for (int i = 0; i < 4; ++i)
#pragma unroll
      for (int j = 0; j < 4; ++j) zacc[i][j] += expf(s[i][j] * SCALEc);
  }

  float* zp = Z + ((size_t)h * Nc + nt * 64) * Nc + mt * 64;
#pragma unroll
  for (int i = 0; i < 4; ++i)
#pragma unroll
    for (int j = 0; j < 4; ++j)
      zp[(size_t)(g * 4 + i) * Nc + c + 16 * j] = zacc[i][j];
}

// ---------------------------------------------------------------------------
// Kernel 3: A[b,h,n,e] = sum_m exp(s)/Z * V -> Acat[b,n,h*128+e] (bf16).
// grid (nt=8, h=4, b=64), block 512. Recomputes S tilewise (flash-style).
// ---------------------------------------------------------------------------
__global__ __launch_bounds__(512) void k_av(
    const unsigned short* __restrict__ Qw, const unsigned short* __restrict__ Kw,
    const unsigned short* __restrict__ Vw, const float* __restrict__ Z,
    unsigned short* __restrict__ Aw) {
  __shared__ float qs[64][132];
  __shared__ float kv[64][132];
  __shared__ float ps[64][68];
  const int tid = threadIdx.x;
  const int nt = blockIdx.x, h = blockIdx.y, b = blockIdx.z;
  const int g = tid >> 4, c = tid & 15;  // g in 0..31
  const int r0 = g * 2;

  const unsigned short* qsrc = Qw + ((size_t)(b * Hc + h) * Nc + nt * 64) * Ec;
#pragma unroll
  for (int i = 0; i < 2; ++i) {
    int f = tid + i * 512;
    int row = f >> 4, c8 = (f & 15) * 8;
    float o[8];
    bf8_to_f(*(const uint4*)(qsrc + (size_t)row * Ec + c8), o);
    *(float4*)&qs[row][c8] = make_float4(o[0], o[1], o[2], o[3]);
    *(float4*)&qs[row][c8 + 4] = make_float4(o[4], o[5], o[6], o[7]);
  }

  float aacc[2][8];
#pragma unroll
  for (int i = 0; i < 2; ++i)
#pragma unroll
    for (int j = 0; j < 8; ++j) aacc[i][j] = 0.f;

  const float* zp = Z + ((size_t)h * Nc + nt * 64) * Nc;

  for (int mt = 0; mt < 8; ++mt) {
    const unsigned short* ksrc = Kw + ((size_t)(b * Hc + h) * Nc + mt * 64) * Ec;
    const unsigned short* vsrc = Vw + ((size_t)(b * Hc + h) * Nc + mt * 64) * Ec;
#pragma unroll
    for (int i = 0; i < 2; ++i) {  // K tile -> kv
      int f = tid + i * 512;
      int row = f >> 4, c8 = (f & 15) * 8;
      float o[8];
      bf8_to_f(*(const uint4*)(ksrc + (size_t)row * Ec + c8), o);
      *(float4*)&kv[row][c8] = make_float4(o[0], o[1], o[2], o[3]);
      *(float4*)&kv[row][c8 + 4] = make_float4(o[4], o[5], o[6], o[7]);
    }
    __syncthreads();  // (A) qs + K ready
    float s[2][4];
#pragma unroll
    for (int i = 0; i < 2; ++i)
#pragma unroll
      for (int j = 0; j < 4; ++j) s[i][j] = 0.f;
#pragma unroll 2
    for (int k = 0; k < 128; ++k) {
      const float a0 = qs[r0][k], a1 = qs[r0 + 1][k];
#pragma unroll
      for (int j = 0; j < 4; ++j) {
        const float bb = kv[c + 16 * j][k];
        s[0][j] = fmaf(a0, bb, s[0][j]);
        s[1][j] = fmaf(a1, bb, s[1][j]);
      }
    }
    __syncthreads();  // (B) K reads done -> safe to overwrite kv with V
#pragma unroll
    for (int i = 0; i < 2; ++i)
#pragma unroll
      for (int j = 0; j < 4; ++j) {
        const float p = expf(s[i][j] * SCALEc) /
                        zp[(size_t)(r0 + i) * Nc + mt * 64 + c + 16 * j];
        ps[r0 + i][c + 16 * j] = p;
      }
#pragma unroll
    for (int i = 0; i < 2; ++i) {  // V tile -> kv
      int f = tid + i * 512;
      int row = f >> 4, c8 = (f & 15) * 8;
      float o[8];
      bf8_to_f(*(const uint4*)(vsrc + (size_t)row * Ec + c8), o);
      *(float4*)&kv[row][c8] = make_float4(o[0], o[1], o[2], o[3]);
      *(float4*)&kv[row][c8 + 4] = make_float4(o[4], o[5], o[6], o[7]);
    }
    __syncthreads();  // (C) ps + V ready
#pragma unroll 2
    for (int m = 0; m < 64; ++m) {
      const float p0 = ps[r0][m], p1 = ps[r0 + 1][m];
#pragma unroll
      for (int j = 0; j < 8; ++j) {
        const float vv = kv[m][c + 16 * j];
        aacc[0][j] = fmaf(p0, vv, aacc[0][j]);
        aacc[1][j] = fmaf(p1, vv, aacc[1][j]);
      }
    }
    __syncthreads();  // (D) PV done -> next mt may overwrite kv/ps
  }

  unsigned short* ap = Aw + ((size_t)(b * Nc) + nt * 64) * (Hc * Ec) + h * Ec;
#pragma unroll
  for (int i = 0; i < 2; ++i)
#pragma unroll
    for (int j = 0; j < 8; ++j)
      ap[(size_t)(r0 + i) * (Hc * Ec) + c + 16 * j] = f2bf(aacc[i][j]);
}

// ---------------------------------------------------------------------------
// Kernel 4: h1 = relu(Acat @ W1 + b1)   [32768,512]x[512,128] -> bf16
// ---------------------------------------------------------------------------
__global__ __launch_bounds__(256) void k_mlp1(
    const unsigned short* __restrict__ Aw, const float* __restrict__ W1,
    const float* __restrict__ b1, unsigned short* __restrict__ h1w) {
  __shared__ float as_[64][68];
  __shared__ float wt[64][132];
  const int tid = threadIdx.x;
  const int r0 = blockIdx.x * 64;
  const int g = tid >> 4, c = tid & 15;
  float acc[4][8];
#pragma unroll
  for (int i = 0; i < 4; ++i)
#pragma unroll
    for (int j = 0; j < 8; ++j) acc[i][j] = 0.f;

  for (int kt = 0; kt < 512; kt += 64) {
#pragma unroll
    for (int i = 0; i < 2; ++i) {  // A tile 64x64 bf16
      int f = tid + i * 256;
      int row = f >> 3, c8 = (f & 7) * 8;
      float o[8];
      bf8_to_f(*(const uint4*)(Aw + (size_t)(r0 + row) * 512 + kt + c8), o);
      *(float4*)&as_[row][c8] = make_float4(o[0], o[1], o[2], o[3]);
      *(float4*)&as_[row][c8 + 4] = make_float4(o[4], o[5], o[6], o[7]);
    }
#pragma unroll
    for (int i = 0; i < 8; ++i) {  // W1 rows kt..kt+63 x 128
      int f = tid + i * 256;
      int row = f >> 5, c4 = (f & 31) * 4;
      *(float4*)&wt[row][c4] = *(const float4*)(W1 + (size_t)(kt + row) * Ec + c4);
    }
    __syncthreads();
#pragma unroll 4
    for (int k = 0; k < 64; ++k) {
      const float a0 = as_[g * 4 + 0][k], a1 = as_[g * 4 + 1][k];
      const float a2 = as_[g * 4 + 2][k], a3 = as_[g * 4 + 3][k];
      float bb[8];
#pragma unroll
      for (int j = 0; j < 8; ++j) bb[j] = wt[k][c + 16 * j];
#pragma unroll
      for (int j = 0; j < 8; ++j) {
        acc[0][j] = fmaf(a0, bb[j], acc[0][j]);
        acc[1][j] = fmaf(a1, bb[j], acc[1][j]);
        acc[2][j] = fmaf(a2, bb[j], acc[2][j]);
        acc[3][j] = fmaf(a3, bb[j], acc[3][j]);
      }
    }
    __syncthreads();
  }
#pragma unroll
  for (int i = 0; i < 4; ++i)
#pragma unroll
    for (int j = 0; j < 8; ++j) {
      const float v = fmaxf(acc[i][j] + b1[c + 16 * j], 0.f);
      h1w[(size_t)(r0 + g * 4 + i) * Ec + c + 16 * j] = f2bf(v);
    }
}

// ---------------------------------------------------------------------------
// Kernel 5: out = LN(x + relu(h1 @ W2 + b2)) * gamma + beta  (fp32 out)
// ---------------------------------------------------------------------------
__global__ __launch_bounds__(256) void k_mlp2(
    const unsigned short* __restrict__ h1w, const float* __restrict__ W2,
    const float* __restrict__ b2, const float* __restrict__ x,
    const float* __restrict__ gamma, const float* __restrict__ beta,
    float* __restrict__ out) {
  __shared__ float hs[64][68];
  __shared__ float wt[64][132];
  const int tid = threadIdx.x;
  const int r0 = blockIdx.x * 64;
  const int g = tid >> 4, c = tid & 15;
  float acc[4][8];
#pragma unroll
  for (int i = 0; i < 4; ++i)
#pragma unroll
    for (int j = 0; j < 8; ++j) acc[i][j] = 0.f;

  for (int kt = 0; kt < 128; kt += 64) {
#pragma unroll
    for (int i = 0; i < 2; ++i) {
      int f = tid + i * 256;
      int row = f >> 3, c8 = (f & 7) * 8;
      float o[8];
      bf8_to_f(*(const uint4*)(h1w + (size_t)(r0 + row) * Ec + kt + c8), o);
      *(float4*)&hs[row][c8] = make_float4(o[0], o[1], o[2], o[3]);
      *(float4*)&hs[row][c8 + 4] = make_float4(o[4], o[5], o[6], o[7]);
    }
#pragma unroll
    for (int i = 0; i < 8; ++i) {
      int f = tid + i * 256;
      int row = f >> 5, c4 = (f & 31) * 4;
      *(float4*)&wt[row][c4] = *(const float4*)(W2 + (size_t)(kt + row) * Ec + c4);
    }
    __syncthreads();
#pragma unroll 4
    for (int k = 0; k < 64; ++k) {
      const float a0 = hs[g * 4 + 0][k], a1 = hs[g * 4 + 1][k];
      const float a2 = hs[g * 4 + 2][k], a3 = hs[g * 4 + 3][k];
      float bb[8];
#pragma unroll
      for (int j = 0; j < 8; ++j) bb[j] = wt[k][c + 16 * j];
#pragma unroll
      for (int j = 0; j < 8; ++j) {
        acc[0][j] = fmaf(a0, bb[j], acc[0][j]);
        acc[1][j] = fmaf(a1, bb[j], acc[1][j]);
        acc[2][j] = fmaf(a2, bb[j], acc[2][j]);
        acc[3][j] = fmaf(a3, bb[j], acc[3][j]);
      }
    }
    __syncthreads();
  }

#pragma unroll
  for (int i = 0; i < 4; ++i) {
    const int row = g * 4 + i;
    float vals[8];
    float s = 0.f, s2 = 0.f;
#pragma unroll
    for (int j = 0; j < 8; ++j) {
      float v = fmaxf(acc[i][j] + b2[c + 16 * j], 0.f) +
                x[(size_t)(r0 + row) * Ec + c + 16 * j];
      vals[j] = v; s += v; s2 += v * v;
    }
    s = red16(s); s2 = red16(s2);
    const float mu = s * (1.f / 128.f);
    const float inv = rsqrtf(s2 * (1.f / 128.f) - mu * mu + EPSc);
#pragma unroll
    for (int j = 0; j < 8; ++j)
      out[(size_t)(r0 + row) * Ec + c + 16 * j] =
          (vals[j] - mu) * inv * gamma[c + 16 * j] + beta[c + 16 * j];
  }
}

extern "C" void kernel_launch(void* const* d_in, const int* in_sizes, int n_in,
                              void* d_out, int out_size, void* d_ws, size_t ws_size,
                              hipStream_t stream) {
  const float* x     = (const float*)d_in[0];
  const float* Wq    = (const float*)d_in[1];
  const float* bq    = (const float*)d_in[2];
  const float* Wk    = (const float*)d_in[3];
  const float* bk    = (const float*)d_in[4];
  const float* Wv    = (const float*)d_in[5];
  const float* bv    = (const float*)d_in[6];
  const float* W1    = (const float*)d_in[7];
  const float* b1    = (const float*)d_in[8];
  const float* W2    = (const float*)d_in[9];
  const float* b2    = (const float*)d_in[10];
  const float* gamma = (const float*)d_in[11];
  const float* beta  = (const float*)d_in[12];
  float* out = (float*)d_out;

  // ws layout (bf16 unless noted): Q,K,V [B,H,N,128]; Acat [B,N,512];
  // h1 [B,N,128]; Z fp32 [H,N,N]. Total ~140 MB.
  unsigned short* Qw  = (unsigned short*)d_ws;
  unsigned short* Kw  = Qw + QKV_SZ;
  unsigned short* Vw  = Kw + QKV_SZ;
  unsigned short* Aw  = Vw + QKV_SZ;
  unsigned short* h1w = Aw + QKV_SZ;
  float* Zw = (float*)(h1w + (size_t)Bc * Nc * Ec);

  k_qkv <<<dim3(512, 12), 256, 0, stream>>>(x, Wq, bq, Wk, bk, Wv, bv, Qw);
  k_z   <<<dim3(8, 8, 4), 256, 0, stream>>>(Qw, Kw, Zw);
  k_av  <<<dim3(8, 4, 64), 512, 0, stream>>>(Qw, Kw, Vw, Zw, Aw);
  k_mlp1<<<dim3(512), 256, 0, stream>>>(Aw, W1, b1, h1w);
  k_mlp2<<<dim3(512), 256, 0, stream>>>(h1w, W2, b2, x, gamma, beta, out);
}

// Round 2
// 219.947 us; speedup vs baseline: 7.3259x; 7.3259x over previous
//
#include <hip/hip_runtime.h>
#include <hip/hip_bf16.h>

// ---------------------------------------------------------------------------
// Round 2: full MFMA (mfma_f32_16x16x32_bf16) pipeline.
// Stages: conv(x,W->bf16, W transposed) -> QK proj+LN -> V proj (transposed,
// LN cross-lane) -> Z partials (sum_b exp) -> Zinv -> AV (flash, /Z) ->
// MLP1 -> MLP2+residual+affine LN.
// ws ~147 MB with aliasing (Aw<-Zp region, h1<-Qw).
// ---------------------------------------------------------------------------

typedef __bf16 bf16x8 __attribute__((ext_vector_type(8)));
typedef float f32x4 __attribute__((ext_vector_type(4)));

constexpr float SCALEc = 1.0f / 11.0f;  // int(sqrt(128)) == 11 (faithful)
constexpr float EPSc = 1e-5f;

#define MFMA(a, b, c) __builtin_amdgcn_mfma_f32_16x16x32_bf16(a, b, c, 0, 0, 0)

static __device__ __forceinline__ unsigned short f2bf(float f) {
  unsigned int x = __float_as_uint(f);
  x += 0x7fffu + ((x >> 16) & 1u);  // RNE
  return (unsigned short)(x >> 16);
}
static __device__ __forceinline__ unsigned int pack2(float a, float b) {
  return (unsigned int)f2bf(a) | ((unsigned int)f2bf(b) << 16);
}
static __device__ __forceinline__ float red16(float v) {
  v += __shfl_xor(v, 1); v += __shfl_xor(v, 2);
  v += __shfl_xor(v, 4); v += __shfl_xor(v, 8);
  return v;
}

// ---------------------------------------------------------------------------
// xb = bf16(x), 4,194,304 elems. grid 2048 x 256, 8 elems/thread.
// ---------------------------------------------------------------------------
__global__ __launch_bounds__(256) void k_conv_x(const float* __restrict__ x,
                                                unsigned short* __restrict__ xb) {
  size_t i = ((size_t)blockIdx.x * 256 + threadIdx.x) * 8;
  float4 a = *(const float4*)(x + i);
  float4 b = *(const float4*)(x + i + 4);
  uint4 o;
  o.x = pack2(a.x, a.y); o.y = pack2(a.z, a.w);
  o.z = pack2(b.x, b.y); o.w = pack2(b.z, b.w);
  *(uint4*)(xb + i) = o;
}

// ---------------------------------------------------------------------------
// Transposed bf16 weights: Wqt|Wkt|Wvt [h][dout][ein] (65536 each),
// W1t [128][512] (65536), W2t [128][128] (16384). grid 1088 x 256.
// ---------------------------------------------------------------------------
__global__ __launch_bounds__(256) void k_conv_w(
    const float* __restrict__ Wq, const float* __restrict__ Wk,
    const float* __restrict__ Wv, const float* __restrict__ W1,
    const float* __restrict__ W2, unsigned short* __restrict__ Wt) {
  int t = blockIdx.x * 256 + threadIdx.x;
  if (t < 196608) {
    int which = t >> 16, r = t & 65535;
    int h = r >> 14, idx = r & 16383;
    int d = idx >> 7, e = idx & 127;
    const float* W = which == 0 ? Wq : (which == 1 ? Wk : Wv);
    Wt[t] = f2bf(W[h * 16384 + e * 128 + d]);
  } else if (t < 262144) {
    int r = t - 196608, d = r >> 9, k = r & 511;
    Wt[t] = f2bf(W1[k * 128 + d]);
  } else if (t < 278528) {
    int r = t - 262144, d = r >> 7, k = r & 127;
    Wt[t] = f2bf(W2[k * 128 + d]);
  }
}

// ---------------------------------------------------------------------------
// Q/K projection + bias + LN(no affine). grid (256 row-tiles, 8=proj*4+h).
// Block: 128 rows x 128 dout, 4 waves x 32 rows. A=xb rows, B=Wt rows(dout).
// ---------------------------------------------------------------------------
__global__ __launch_bounds__(256, 2) void k_qkv(
    const unsigned short* __restrict__ xb, const unsigned short* __restrict__ Wt,
    const float* __restrict__ bq, const float* __restrict__ bk,
    unsigned short* __restrict__ Qw, unsigned short* __restrict__ Kw) {
  __shared__ unsigned short xs[128][136];
  __shared__ unsigned short wt[128][136];
  const int tid = threadIdx.x;
  const int proj = blockIdx.y >> 2, h = blockIdx.y & 3;
  const int r0 = blockIdx.x * 128;
  const unsigned short* wsrc = Wt + proj * 65536 + h * 16384;
  const float* bias = (proj == 0 ? bq : bk) + h * 128;
  unsigned short* dst =
      (proj == 0 ? Qw : Kw) + ((size_t)((r0 >> 9) * 4 + h) * 512 + (r0 & 511)) * 128;

#pragma unroll
  for (int i = 0; i < 8; ++i) {
    int f = tid + i * 256, row = f >> 4, c8 = (f & 15) * 8;
    *(uint4*)&xs[row][c8] = *(const uint4*)(xb + (size_t)(r0 + row) * 128 + c8);
    *(uint4*)&wt[row][c8] = *(const uint4*)(wsrc + row * 128 + c8);
  }
  __syncthreads();

  const int wid = tid >> 6, lane = tid & 63, lr = lane & 15, lg = lane >> 4;
  const int wr0 = wid * 32;
  f32x4 acc[2][8];
#pragma unroll
  for (int i = 0; i < 2; ++i)
#pragma unroll
    for (int j = 0; j < 8; ++j) acc[i][j] = (f32x4)0.f;

#pragma unroll
  for (int ksi = 0; ksi < 4; ++ksi) {
    const int k0 = ksi * 32 + lg * 8;
    bf16x8 af0 = *(const bf16x8*)&xs[wr0 + lr][k0];
    bf16x8 af1 = *(const bf16x8*)&xs[wr0 + 16 + lr][k0];
#pragma unroll
    for (int fj = 0; fj < 8; ++fj) {
      bf16x8 bfr = *(const bf16x8*)&wt[fj * 16 + lr][k0];
      acc[0][fj] = MFMA(af0, bfr, acc[0][fj]);
      acc[1][fj] = MFMA(af1, bfr, acc[1][fj]);
    }
  }

  float bb[8];
#pragma unroll
  for (int fj = 0; fj < 8; ++fj) bb[fj] = bias[fj * 16 + lr];
#pragma unroll
  for (int fi = 0; fi < 2; ++fi)
#pragma unroll
    for (int r = 0; r < 4; ++r) {
      const int row = wr0 + fi * 16 + lg * 4 + r;
      float v[8], s = 0.f, s2 = 0.f;
#pragma unroll
      for (int fj = 0; fj < 8; ++fj) {
        v[fj] = acc[fi][fj][r] + bb[fj];
        s += v[fj]; s2 += v[fj] * v[fj];
      }
      s = red16(s); s2 = red16(s2);
      const float mu = s * (1.f / 128.f);
      const float inv = rsqrtf(s2 * (1.f / 128.f) - mu * mu + EPSc);
#pragma unroll
      for (int fj = 0; fj < 8; ++fj)
        dst[(size_t)row * 128 + fj * 16 + lr] = f2bf((v[fj] - mu) * inv);
    }
}

// ---------------------------------------------------------------------------
// V projection TRANSPOSED: Vt[b,h,e,n] = LN_e(x@Wv + bv). D = Wvt x xb^T.
// grid (256 n-tiles, 4 h). Wave: all 128 eout x 32 n. LN across rows via
// shfl_xor(16/32).
// ---------------------------------------------------------------------------
__global__ __launch_bounds__(256, 2) void k_vproj(
    const unsigned short* __restrict__ xb, const unsigned short* __restrict__ Wt,
    const float* __restrict__ bv, unsigned short* __restrict__ Vtw) {
  __shared__ unsigned short xs[128][136];
  __shared__ unsigned short wv[128][136];
  const int tid = threadIdx.x;
  const int h = blockIdx.y;
  const int n0 = blockIdx.x * 128;
  const unsigned short* wsrc = Wt + 131072 + h * 16384;
#pragma unroll
  for (int i = 0; i < 8; ++i) {
    int f = tid + i * 256, row = f >> 4, c8 = (f & 15) * 8;
    *(uint4*)&xs[row][c8] = *(const uint4*)(xb + (size_t)(n0 + row) * 128 + c8);
    *(uint4*)&wv[row][c8] = *(const uint4*)(wsrc + row * 128 + c8);
  }
  __syncthreads();
  const int wid = tid >> 6, lane = tid & 63, lr = lane & 15, lg = lane >> 4;
  const int wn0 = wid * 32;
  f32x4 acc[8][2];
#pragma unroll
  for (int i = 0; i < 8; ++i) {
    acc[i][0] = (f32x4)0.f; acc[i][1] = (f32x4)0.f;
  }
#pragma unroll
  for (int ksi = 0; ksi < 4; ++ksi) {
    const int k0 = ksi * 32 + lg * 8;
    bf16x8 bf0 = *(const bf16x8*)&xs[wn0 + lr][k0];
    bf16x8 bf1 = *(const bf16x8*)&xs[wn0 + 16 + lr][k0];
#pragma unroll
    for (int fi = 0; fi < 8; ++fi) {
      bf16x8 af = *(const bf16x8*)&wv[fi * 16 + lr][k0];
      acc[fi][0] = MFMA(af, bf0, acc[fi][0]);
      acc[fi][1] = MFMA(af, bf1, acc[fi][1]);
    }
  }
  // bias per row (eout)
#pragma unroll
  for (int fi = 0; fi < 8; ++fi)
#pragma unroll
    for (int r = 0; r < 4; ++r) {
      const float bvv = bv[h * 128 + fi * 16 + lg * 4 + r];
      acc[fi][0][r] += bvv; acc[fi][1][r] += bvv;
    }
  const int gb = n0 >> 9;
  unsigned short* base = Vtw + (size_t)(gb * 4 + h) * 128 * 512;
#pragma unroll
  for (int fj = 0; fj < 2; ++fj) {
    float s = 0.f, s2 = 0.f;
#pragma unroll
    for (int fi = 0; fi < 8; ++fi)
#pragma unroll
      for (int r = 0; r < 4; ++r) {
        const float v = acc[fi][fj][r];
        s += v; s2 += v * v;
      }
    s += __shfl_xor(s, 16); s += __shfl_xor(s, 32);
    s2 += __shfl_xor(s2, 16); s2 += __shfl_xor(s2, 32);
    const float mu = s * (1.f / 128.f);
    const float inv = rsqrtf(s2 * (1.f / 128.f) - mu * mu + EPSc);
    const int nl = (n0 & 511) + wn0 + fj * 16 + lr;
#pragma unroll
    for (int fi = 0; fi < 8; ++fi)
#pragma unroll
      for (int r = 0; r < 4; ++r) {
        const int eout = fi * 16 + lg * 4 + r;
        base[(size_t)eout * 512 + nl] = f2bf((acc[fi][fj][r] - mu) * inv);
      }
  }
}

// ---------------------------------------------------------------------------
// Z partials: Zp[bs,h,n,m] = sum_{b in group} exp(QK/11). grid (16,4,4):
// x = nt + 4*bs, y = mt, z = h. Block: 128n x 128m, 16 b per group.
// ---------------------------------------------------------------------------
__global__ __launch_bounds__(256, 2) void k_z(
    const unsigned short* __restrict__ Qw, const unsigned short* __restrict__ Kw,
    float* __restrict__ Zp) {
  __shared__ unsigned short qs[128][136];
  __shared__ unsigned short ks_[128][136];
  const int tid = threadIdx.x;
  const int nt = blockIdx.x & 3, bs = blockIdx.x >> 2;
  const int mt = blockIdx.y, h = blockIdx.z;
  const int wid = tid >> 6, lane = tid & 63, lr = lane & 15, lg = lane >> 4;
  f32x4 zacc[2][8];
#pragma unroll
  for (int i = 0; i < 2; ++i)
#pragma unroll
    for (int j = 0; j < 8; ++j) zacc[i][j] = (f32x4)0.f;

  for (int b = bs * 16; b < bs * 16 + 16; ++b) {
    const unsigned short* qsrc = Qw + ((size_t)(b * 4 + h) * 512 + nt * 128) * 128;
    const unsigned short* ksrc = Kw + ((size_t)(b * 4 + h) * 512 + mt * 128) * 128;
#pragma unroll
    for (int i = 0; i < 8; ++i) {
      int f = tid + i * 256, row = f >> 4, c8 = (f & 15) * 8;
      *(uint4*)&qs[row][c8] = *(const uint4*)(qsrc + (size_t)row * 128 + c8);
      *(uint4*)&ks_[row][c8] = *(const uint4*)(ksrc + (size_t)row * 128 + c8);
    }
    __syncthreads();
    f32x4 s[2][8];
#pragma unroll
    for (int i = 0; i < 2; ++i)
#pragma unroll
      for (int j = 0; j < 8; ++j) s[i][j] = (f32x4)0.f;
#pragma unroll
    for (int ksi = 0; ksi < 4; ++ksi) {
      const int k0 = ksi * 32 + lg * 8;
      bf16x8 af0 = *(const bf16x8*)&qs[wid * 32 + lr][k0];
      bf16x8 af1 = *(const bf16x8*)&qs[wid * 32 + 16 + lr][k0];
#pragma unroll
      for (int fj = 0; fj < 8; ++fj) {
        bf16x8 bfr = *(const bf16x8*)&ks_[fj * 16 + lr][k0];
        s[0][fj] = MFMA(af0, bfr, s[0][fj]);
        s[1][fj] = MFMA(af1, bfr, s[1][fj]);
      }
    }
    __syncthreads();
#pragma unroll
    for (int fi = 0; fi < 2; ++fi)
#pragma unroll
      for (int fj = 0; fj < 8; ++fj)
#pragma unroll
        for (int r = 0; r < 4; ++r)
          zacc[fi][fj][r] += __expf(s[fi][fj][r] * SCALEc);
  }
#pragma unroll
  for (int fi = 0; fi < 2; ++fi)
#pragma unroll
    for (int r = 0; r < 4; ++r) {
      const int n = nt * 128 + wid * 32 + fi * 16 + lg * 4 + r;
      float* zp = Zp + ((size_t)(bs * 4 + h) * 512 + n) * 512 + mt * 128;
#pragma unroll
      for (int fj = 0; fj < 8; ++fj) zp[fj * 16 + lr] = zacc[fi][fj][r];
    }
}

// ---------------------------------------------------------------------------
// Zinv = 1 / sum_bs Zp. 1,048,576 elems, 4/thread. grid 1024 x 256.
// ---------------------------------------------------------------------------
__global__ __launch_bounds__(256) void k_zred(const float* __restrict__ Zp,
                                              float* __restrict__ Zinv) {
  size_t i = ((size_t)blockIdx.x * 256 + threadIdx.x) * 4;
  float4 s = *(const float4*)(Zp + i);
#pragma unroll
  for (int p = 1; p < 4; ++p) {
    float4 t = *(const float4*)(Zp + (size_t)p * 1048576 + i);
    s.x += t.x; s.y += t.y; s.z += t.z; s.w += t.w;
  }
  float4 o = make_float4(1.f / s.x, 1.f / s.y, 1.f / s.z, 1.f / s.w);
  *(float4*)(Zinv + i) = o;
}

// ---------------------------------------------------------------------------
// AV: A[b,h,n,e] = sum_m exp(QK/11)*Zinv * V -> Aw[b,n, h*128+e] bf16.
// grid (8 nt, 4 h, 64 b). Block 64n, 4 waves x 16n; loop 8 m-tiles of 64.
// ---------------------------------------------------------------------------
__global__ __launch_bounds__(256, 2) void k_av(
    const unsigned short* __restrict__ Qw, const unsigned short* __restrict__ Kw,
    const unsigned short* __restrict__ Vtw, const float* __restrict__ Zinv,
    unsigned short* __restrict__ Aw) {
  __shared__ unsigned short qs[64][136];
  __shared__ unsigned short kt[64][136];
  __shared__ unsigned short vt[128][72];
  __shared__ unsigned short ps[64][72];
  const int tid = threadIdx.x;
  const int nt = blockIdx.x, h = blockIdx.y, b = blockIdx.z;
  const int wid = tid >> 6, lane = tid & 63, lr = lane & 15, lg = lane >> 4;
  const size_t bh = (size_t)(b * 4 + h);

  const unsigned short* qsrc = Qw + (bh * 512 + nt * 64) * 128;
#pragma unroll
  for (int i = 0; i < 4; ++i) {
    int f = tid + i * 256, row = f >> 4, c8 = (f & 15) * 8;
    *(uint4*)&qs[row][c8] = *(const uint4*)(qsrc + (size_t)row * 128 + c8);
  }
  f32x4 acc[8];
#pragma unroll
  for (int i = 0; i < 8; ++i) acc[i] = (f32x4)0.f;
  const float* zbase = Zinv + ((size_t)h * 512 + nt * 64) * 512;

  for (int mt = 0; mt < 8; ++mt) {
    const unsigned short* ksrc = Kw + (bh * 512 + mt * 64) * 128;
    const unsigned short* vsrc = Vtw + bh * 65536 + mt * 64;
#pragma unroll
    for (int i = 0; i < 4; ++i) {
      int f = tid + i * 256;
      int row = f >> 4, c8 = (f & 15) * 8;
      *(uint4*)&kt[row][c8] = *(const uint4*)(ksrc + (size_t)row * 128 + c8);
      int vrow = f >> 3, vc8 = (f & 7) * 8;
      *(uint4*)&vt[vrow][vc8] = *(const uint4*)(vsrc + (size_t)vrow * 512 + vc8);
    }
    __syncthreads();
    // S = Q K^T: 16n x 64m per wave
    f32x4 s[4];
#pragma unroll
    for (int i = 0; i < 4; ++i) s[i] = (f32x4)0.f;
#pragma unroll
    for (int ksi = 0; ksi < 4; ++ksi) {
      const int k0 = ksi * 32 + lg * 8;
      bf16x8 a = *(const bf16x8*)&qs[wid * 16 + lr][k0];
#pragma unroll
      for (int fm = 0; fm < 4; ++fm) {
        bf16x8 bfr = *(const bf16x8*)&kt[fm * 16 + lr][k0];
        s[fm] = MFMA(a, bfr, s[fm]);
      }
    }
    // P = exp(s/11) * Zinv -> ps (each wave writes/reads only its 16 rows)
#pragma unroll
    for (int fm = 0; fm < 4; ++fm)
#pragma unroll
      for (int r = 0; r < 4; ++r) {
        const int n = wid * 16 + lg * 4 + r;
        const int m = fm * 16 + lr;
        const float p = __expf(s[fm][r] * SCALEc) *
                        zbase[(size_t)n * 512 + mt * 64 + m];
        ps[n][m] = f2bf(p);
      }
    // PV: acc[n][e] += P[n][m] * Vt[e][m]
#pragma unroll
    for (int ksm = 0; ksm < 2; ++ksm) {
      bf16x8 pa = *(const bf16x8*)&ps[wid * 16 + lr][ksm * 32 + lg * 8];
#pragma unroll
      for (int fe = 0; fe < 8; ++fe) {
        bf16x8 bv_ = *(const bf16x8*)&vt[fe * 16 + lr][ksm * 32 + lg * 8];
        acc[fe] = MFMA(pa, bv_, acc[fe]);
      }
    }
    __syncthreads();
  }
  unsigned short* adst = Aw + ((size_t)(b * 512) + nt * 64) * 512 + h * 128;
#pragma unroll
  for (int r = 0; r < 4; ++r) {
    const int n = wid * 16 + lg * 4 + r;
#pragma unroll
    for (int fe = 0; fe < 8; ++fe)
      adst[(size_t)n * 512 + fe * 16 + lr] = f2bf(acc[fe][r]);
  }
}

// ---------------------------------------------------------------------------
// MLP1: h1 = relu(Acat @ W1 + b1), [32768,512]x[512,128]. grid 256.
// ---------------------------------------------------------------------------
__global__ __launch_bounds__(256, 2) void k_mlp1(
    const unsigned short* __restrict__ Aw, const unsigned short* __restrict__ Wt,
    const float* __restrict__ b1, unsigned short* __restrict__ h1w) {
  __shared__ unsigned short as_[128][136];
  __shared__ unsigned short w1[128][136];
  const int tid = threadIdx.x;
  const int wid = tid >> 6, lane = tid & 63, lr = lane & 15, lg = lane >> 4;
  const int r0 = blockIdx.x * 128;
  const unsigned short* w1t = Wt + 196608;
  f32x4 acc[2][8];
#pragma unroll
  for (int i = 0; i < 2; ++i)
#pragma unroll
    for (int j = 0; j < 8; ++j) acc[i][j] = (f32x4)0.f;

  for (int ktile = 0; ktile < 4; ++ktile) {
#pragma unroll
    for (int i = 0; i < 8; ++i) {
      int f = tid + i * 256, row = f >> 4, c8 = (f & 15) * 8;
      *(uint4*)&as_[row][c8] =
          *(const uint4*)(Aw + (size_t)(r0 + row) * 512 + ktile * 128 + c8);
      *(uint4*)&w1[row][c8] =
          *(const uint4*)(w1t + (size_t)row * 512 + ktile * 128 + c8);
    }
    __syncthreads();
#pragma unroll
    for (int ksi = 0; ksi < 4; ++ksi) {
      const int k0 = ksi * 32 + lg * 8;
      bf16x8 af0 = *(const bf16x8*)&as_[wid * 32 + lr][k0];
      bf16x8 af1 = *(const bf16x8*)&as_[wid * 32 + 16 + lr][k0];
#pragma unroll
      for (int fj = 0; fj < 8; ++fj) {
        bf16x8 bfr = *(const bf16x8*)&w1[fj * 16 + lr][k0];
        acc[0][fj] = MFMA(af0, bfr, acc[0][fj]);
        acc[1][fj] = MFMA(af1, bfr, acc[1][fj]);
      }
    }
    __syncthreads();
  }
  float bb[8];
#pragma unroll
  for (int fj = 0; fj < 8; ++fj) bb[fj] = b1[fj * 16 + lr];
#pragma unroll
  for (int fi = 0; fi < 2; ++fi)
#pragma unroll
    for (int r = 0; r < 4; ++r) {
      const int gr = r0 + wid * 32 + fi * 16 + lg * 4 + r;
#pragma unroll
      for (int fj = 0; fj < 8; ++fj)
        h1w[(size_t)gr * 128 + fj * 16 + lr] =
            f2bf(fmaxf(acc[fi][fj][r] + bb[fj], 0.f));
    }
}

// ---------------------------------------------------------------------------
// MLP2 + residual + affine LN -> out f32. grid 256.
// ---------------------------------------------------------------------------
__global__ __launch_bounds__(256, 2) void k_mlp2(
    const unsigned short* __restrict__ h1w, const unsigned short* __restrict__ Wt,
    const float* __restrict__ b2, const float* __restrict__ x,
    const float* __restrict__ gamma, const float* __restrict__ beta,
    float* __restrict__ out) {
  __shared__ unsigned short hs[128][136];
  __shared__ unsigned short w2[128][136];
  const int tid = threadIdx.x;
  const int wid = tid >> 6, lane = tid & 63, lr = lane & 15, lg = lane >> 4;
  const int r0 = blockIdx.x * 128;
  const unsigned short* w2t = Wt + 262144;
#pragma unroll
  for (int i = 0; i < 8; ++i) {
    int f = tid + i * 256, row = f >> 4, c8 = (f & 15) * 8;
    *(uint4*)&hs[row][c8] = *(const uint4*)(h1w + (size_t)(r0 + row) * 128 + c8);
    *(uint4*)&w2[row][c8] = *(const uint4*)(w2t + (size_t)row * 128 + c8);
  }
  __syncthreads();
  f32x4 acc[2][8];
#pragma unroll
  for (int i = 0; i < 2; ++i)
#pragma unroll
    for (int j = 0; j < 8; ++j) acc[i][j] = (f32x4)0.f;
#pragma unroll
  for (int ksi = 0; ksi < 4; ++ksi) {
    const int k0 = ksi * 32 + lg * 8;
    bf16x8 af0 = *(const bf16x8*)&hs[wid * 32 + lr][k0];
    bf16x8 af1 = *(const bf16x8*)&hs[wid * 32 + 16 + lr][k0];
#pragma unroll
    for (int fj = 0; fj < 8; ++fj) {
      bf16x8 bfr = *(const bf16x8*)&w2[fj * 16 + lr][k0];
      acc[0][fj] = MFMA(af0, bfr, acc[0][fj]);
      acc[1][fj] = MFMA(af1, bfr, acc[1][fj]);
    }
  }
  float bb[8], gm[8], bt[8];
#pragma unroll
  for (int fj = 0; fj < 8; ++fj) {
    bb[fj] = b2[fj * 16 + lr];
    gm[fj] = gamma[fj * 16 + lr];
    bt[fj] = beta[fj * 16 + lr];
  }
#pragma unroll
  for (int fi = 0; fi < 2; ++fi)
#pragma unroll
    for (int r = 0; r < 4; ++r) {
      const int gr = r0 + wid * 32 + fi * 16 + lg * 4 + r;
      float v[8], s = 0.f, s2 = 0.f;
#pragma unroll
      for (int fj = 0; fj < 8; ++fj) {
        v[fj] = fmaxf(acc[fi][fj][r] + bb[fj], 0.f) +
                x[(size_t)gr * 128 + fj * 16 + lr];
        s += v[fj]; s2 += v[fj] * v[fj];
      }
      s = red16(s); s2 = red16(s2);
      const float mu = s * (1.f / 128.f);
      const float inv = rsqrtf(s2 * (1.f / 128.f) - mu * mu + EPSc);
#pragma unroll
      for (int fj = 0; fj < 8; ++fj)
        out[(size_t)gr * 128 + fj * 16 + lr] =
            (v[fj] - mu) * inv * gm[fj] + bt[fj];
    }
}

extern "C" void kernel_launch(void* const* d_in, const int* in_sizes, int n_in,
                              void* d_out, int out_size, void* d_ws, size_t ws_size,
                              hipStream_t stream) {
  const float* x     = (const float*)d_in[0];
  const float* Wq    = (const float*)d_in[1];
  const float* bq    = (const float*)d_in[2];
  const float* Wk    = (const float*)d_in[3];
  const float* bk    = (const float*)d_in[4];
  const float* Wv    = (const float*)d_in[5];
  const float* bv    = (const float*)d_in[6];
  const float* W1    = (const float*)d_in[7];
  const float* b1    = (const float*)d_in[8];
  const float* W2    = (const float*)d_in[9];
  const float* b2    = (const float*)d_in[10];
  const float* gamma = (const float*)d_in[11];
  const float* beta  = (const float*)d_in[12];
  float* out = (float*)d_out;

  // ws layout (elements):
  //  xb      ushort  4,194,304
  //  Qw      ushort 16,777,216   (aliased later as h1w)
  //  Kw      ushort 16,777,216
  //  Vtw     ushort 16,777,216
  //  ZpA     ushort 16,777,216   (Zp f32 4,194,304 first, then reused as Aw)
  //  Zinv    f32     1,048,576
  //  Wts     ushort    278,528
  // total ~147 MB
  unsigned short* xb  = (unsigned short*)d_ws;
  unsigned short* Qw  = xb + 4194304;
  unsigned short* Kw  = Qw + 16777216;
  unsigned short* Vtw = Kw + 16777216;
  unsigned short* ZpA = Vtw + 16777216;
  float* Zp = (float*)ZpA;
  unsigned short* Aw = ZpA;
  float* Zinv = (float*)(ZpA + 16777216);
  unsigned short* Wts = (unsigned short*)(Zinv + 1048576);
  unsigned short* h1w = Qw;  // alias: Qw dead after k_av

  k_conv_x<<<2048, 256, 0, stream>>>(x, xb);
  k_conv_w<<<1088, 256, 0, stream>>>(Wq, Wk, Wv, W1, W2, Wts);
  k_qkv  <<<dim3(256, 8), 256, 0, stream>>>(xb, Wts, bq, bk, Qw, Kw);
  k_vproj<<<dim3(256, 4), 256, 0, stream>>>(xb, Wts, bv, Vtw);
  k_z    <<<dim3(16, 4, 4), 256, 0, stream>>>(Qw, Kw, Zp);
  k_zred <<<1024, 256, 0, stream>>>(Zp, Zinv);
  k_av   <<<dim3(8, 4, 64), 256, 0, stream>>>(Qw, Kw, Vtw, Zinv, Aw);
  k_mlp1 <<<256, 256, 0, stream>>>(Aw, Wts, b1, h1w);
  k_mlp2 <<<256, 256, 0, stream>>>(h1w, Wts, b2, x, gamma, beta, out);
}